// Round 3
// baseline (500.259 us; speedup 1.0000x reference)
//
#include <hip/hip_runtime.h>
#include <hip/hip_cooperative_groups.h>

namespace cg = cooperative_groups;

#define B_ 128
#define N_ 256
#define M_ 1024
#define EPS_ 1e-16f
#define NORM_EPS_ 1e-8f

#define GRID_ 1024
#define ROWS_PER_BLOCK_ 32      // (B_*N_) / GRID_
#define SPLIT_ 8                // GRID_ / B_  (blocks per batch)
#define NSUB_ 32                // N_ / SPLIT_

typedef float f32x4 __attribute__((ext_vector_type(4)));

__device__ __forceinline__ float wave_reduce_sum(float v) {
#pragma unroll
    for (int off = 32; off; off >>= 1) v += __shfl_xor(v, off, 64);
    return v;
}

__device__ __forceinline__ float wave_reduce_max(float v) {
#pragma unroll
    for (int off = 32; off; off >>= 1) v = fmaxf(v, __shfl_xor(v, off, 64));
    return v;
}

// One cooperative kernel, 1024 blocks x 256 threads, 4 blocks/CU.
// Phase A: per-row dot(mem+eps, k+eps), ||mem+eps||^2  (block -> its 32 rows)
// Phase B: per-batch weight pipeline (blocks 0..127)
// Phase C: erase/add write + fused read partials (same 32 rows -> L2/L3 hot)
__global__ void __launch_bounds__(256, 4)
ntm_fused_kernel(const float* __restrict__ memory,
                 const float* __restrict__ k,
                 const float* __restrict__ beta,
                 const float* __restrict__ g,
                 const float* __restrict__ s,
                 const float* __restrict__ gamma,
                 const float* __restrict__ w_prev,
                 const float* __restrict__ e,
                 const float* __restrict__ a,
                 float* __restrict__ read_out,
                 float* __restrict__ newmem_out,
                 float* __restrict__ w_out,
                 float* __restrict__ dot_ws,
                 float* __restrict__ mnorm2_ws) {
    cg::grid_group grid = cg::this_grid();

    const int tid  = threadIdx.x;           // 0..255
    const int lane = tid & 63;
    const int wave = tid >> 6;
    const int blk  = blockIdx.x;

    __shared__ float red[4];
    __shared__ float s_wg[N_];
    __shared__ float s_w[NSUB_];

    // ---------------- Phase A ----------------
    // zero-init read_out (d_out is poisoned 0xAA): 1024 blocks * 128 = B_*M_
    if (tid < 128) read_out[blk * 128 + tid] = 0.f;

    {
        const int b = blk >> 3;             // blk / SPLIT_
        const f32x4* __restrict__ krow = (const f32x4*)(k + (size_t)b * M_);
        for (int j = 0; j < 8; ++j) {       // 8 rows per wave
            const int row = blk * ROWS_PER_BLOCK_ + wave * 8 + j;
            const f32x4* __restrict__ mrow = (const f32x4*)(memory + (size_t)row * M_);
            float dacc = 0.f, nacc = 0.f;
#pragma unroll
            for (int it = 0; it < 4; ++it) {
                const int idx = it * 64 + lane;
                f32x4 mv = mrow[idx];
                f32x4 kv = krow[idx];
                float m0 = mv.x + EPS_, m1 = mv.y + EPS_, m2 = mv.z + EPS_, m3 = mv.w + EPS_;
                float c0 = kv.x + EPS_, c1 = kv.y + EPS_, c2 = kv.z + EPS_, c3 = kv.w + EPS_;
                dacc += m0 * c0 + m1 * c1 + m2 * c2 + m3 * c3;
                nacc += m0 * m0 + m1 * m1 + m2 * m2 + m3 * m3;
            }
            dacc = wave_reduce_sum(dacc);
            nacc = wave_reduce_sum(nacc);
            if (lane == 0) {
                dot_ws[row]    = dacc;
                mnorm2_ws[row] = nacc;
            }
        }
    }

    grid.sync();

    // ---------------- Phase B (blocks 0..127, one per batch) ----------------
    if (blk < B_) {
        const int b = blk;
        const int n = tid;

        // knorm
        f32x4 kv = ((const f32x4*)(k + (size_t)b * M_))[tid];
        float k0 = kv.x + EPS_, k1 = kv.y + EPS_, k2 = kv.z + EPS_, k3 = kv.w + EPS_;
        float kk = k0 * k0 + k1 * k1 + k2 * k2 + k3 * k3;
        kk = wave_reduce_sum(kk);
        if (lane == 0) red[wave] = kk;
        __syncthreads();
        const float knorm = fmaxf(sqrtf(red[0] + red[1] + red[2] + red[3]), NORM_EPS_);
        __syncthreads();

        // cosine + beta
        const float mnorm = fmaxf(sqrtf(mnorm2_ws[(size_t)b * N_ + n]), NORM_EPS_);
        const float cosv  = dot_ws[(size_t)b * N_ + n] / (mnorm * knorm);
        const float x     = beta[b] * cosv;

        // softmax over n
        float mx = wave_reduce_max(x);
        if (lane == 0) red[wave] = mx;
        __syncthreads();
        mx = fmaxf(fmaxf(red[0], red[1]), fmaxf(red[2], red[3]));
        __syncthreads();
        const float ex = __expf(x - mx);
        float es = wave_reduce_sum(ex);
        if (lane == 0) red[wave] = es;
        __syncthreads();
        es = red[0] + red[1] + red[2] + red[3];
        __syncthreads();
        const float w_c = ex / es;

        // interpolate
        const float gb  = g[b];
        const float w_g = gb * w_c + (1.f - gb) * w_prev[(size_t)b * N_ + n];
        s_wg[n] = w_g;
        __syncthreads();

        // circular 3-tap shift
        const float s0 = s[b * 3 + 0], s1 = s[b * 3 + 1], s2 = s[b * 3 + 2];
        const float w_t = s0 * s_wg[(n + N_ - 1) & (N_ - 1)]
                        + s1 * s_wg[n]
                        + s2 * s_wg[(n + 1) & (N_ - 1)];

        // sharpen
        const float w_pow = powf(w_t, gamma[b]);
        float ps = wave_reduce_sum(w_pow);
        if (lane == 0) red[wave] = ps;
        __syncthreads();
        ps = red[0] + red[1] + red[2] + red[3];

        w_out[(size_t)b * N_ + n] = w_pow / (ps + EPS_);
    }

    grid.sync();

    // ---------------- Phase C ----------------
    {
        const int b    = blk >> 3;
        const int part = blk & 7;

        if (tid < NSUB_) s_w[tid] = w_out[(size_t)b * N_ + part * NSUB_ + tid];
        __syncthreads();

        const f32x4 ev = ((const f32x4*)(e + (size_t)b * M_))[tid];
        const f32x4 av = ((const f32x4*)(a + (size_t)b * M_))[tid];

        const size_t base = (size_t)b * N_ * M_;
        f32x4 racc = {0.f, 0.f, 0.f, 0.f};

#pragma unroll 4
        for (int j = 0; j < NSUB_; ++j) {
            const int n = part * NSUB_ + j;
            const f32x4* mrow = (const f32x4*)(memory + base + (size_t)n * M_);
            const f32x4 mv = __builtin_nontemporal_load(mrow + tid);
            const float wn = s_w[j];
            f32x4 nv;
            nv.x = mv.x * (1.f - wn * ev.x) + wn * av.x;
            nv.y = mv.y * (1.f - wn * ev.y) + wn * av.y;
            nv.z = mv.z * (1.f - wn * ev.z) + wn * av.z;
            nv.w = mv.w * (1.f - wn * ev.w) + wn * av.w;
            __builtin_nontemporal_store(nv, (f32x4*)(newmem_out + base + (size_t)n * M_) + tid);
            racc.x += wn * nv.x;
            racc.y += wn * nv.y;
            racc.z += wn * nv.z;
            racc.w += wn * nv.w;
        }

        float* rrow = read_out + (size_t)b * M_ + tid * 4;
        atomicAdd(rrow + 0, racc.x);
        atomicAdd(rrow + 1, racc.y);
        atomicAdd(rrow + 2, racc.z);
        atomicAdd(rrow + 3, racc.w);
    }
}

extern "C" void kernel_launch(void* const* d_in, const int* in_sizes, int n_in,
                              void* d_out, int out_size, void* d_ws, size_t ws_size,
                              hipStream_t stream) {
    (void)in_sizes; (void)n_in; (void)out_size; (void)ws_size;

    const float* memory = (const float*)d_in[0];
    const float* k      = (const float*)d_in[1];
    const float* beta   = (const float*)d_in[2];
    const float* g      = (const float*)d_in[3];
    const float* s      = (const float*)d_in[4];
    const float* gamma  = (const float*)d_in[5];
    const float* w_prev = (const float*)d_in[6];
    const float* e      = (const float*)d_in[7];
    const float* a      = (const float*)d_in[8];

    float* out        = (float*)d_out;
    float* read_out   = out;                                 // B*M
    float* newmem_out = out + (size_t)B_ * M_;               // B*N*M
    float* w_out      = newmem_out + (size_t)B_ * N_ * M_;   // B*N

    float* ws        = (float*)d_ws;
    float* dot_ws    = ws;                                   // B*N
    float* mnorm2_ws = ws + (size_t)B_ * N_;                 // B*N

    void* args[] = {
        (void*)&memory, (void*)&k, (void*)&beta, (void*)&g, (void*)&s,
        (void*)&gamma, (void*)&w_prev, (void*)&e, (void*)&a,
        (void*)&read_out, (void*)&newmem_out, (void*)&w_out,
        (void*)&dot_ws, (void*)&mnorm2_ws
    };
    hipLaunchCooperativeKernel((const void*)ntm_fused_kernel,
                               dim3(GRID_), dim3(256), args, 0, stream);
}

// Round 4
// 270.929 us; speedup vs baseline: 1.8465x; 1.8465x over previous
//
#include <hip/hip_runtime.h>

#define B_ 128
#define N_ 256
#define M_ 1024
#define EPS_ 1e-16f
#define NORM_EPS_ 1e-8f

#define SPLIT_ 8                 // write/read blocks per batch
#define NSUB_ (N_ / SPLIT_)      // 32 rows per block

typedef float f32x4 __attribute__((ext_vector_type(4)));

__device__ __forceinline__ float wave_reduce_sum(float v) {
#pragma unroll
    for (int off = 32; off; off >>= 1) v += __shfl_xor(v, off, 64);
    return v;
}

__device__ __forceinline__ float wave_reduce_max(float v) {
#pragma unroll
    for (int off = 32; off; off >>= 1) v = fmaxf(v, __shfl_xor(v, off, 64));
    return v;
}

// ---------------- Pass 1: per-row dot(mem+eps, k+eps) and ||mem+eps||^2 ----------------
// grid: (B*N)/4 = 8192 blocks, 256 threads (4 waves, one wave per row).
// Also zero-inits read_out (B*M = 512 blocks x 256 threads worth).
__global__ void sim_kernel(const float* __restrict__ memory,
                           const float* __restrict__ k,
                           float* __restrict__ dot_out,
                           float* __restrict__ mnorm2_out,
                           float* __restrict__ read_out) {
    const int wave = threadIdx.x >> 6;
    const int lane = threadIdx.x & 63;
    const int row  = blockIdx.x * 4 + wave;        // [0, B*N)
    const int b    = row >> 8;                     // N = 256

    // zero-init the read output (d_out is poisoned 0xAA before every launch)
    if (blockIdx.x < (B_ * M_) / 256) {
        read_out[blockIdx.x * 256 + threadIdx.x] = 0.f;
    }

    const f32x4* __restrict__ mrow = (const f32x4*)(memory + (size_t)row * M_);
    const f32x4* __restrict__ krow = (const f32x4*)(k + (size_t)b * M_);

    float dacc = 0.f, nacc = 0.f;
#pragma unroll
    for (int it = 0; it < 4; ++it) {
        const int idx = it * 64 + lane;            // f32x4 index in [0,256)
        f32x4 mv = mrow[idx];
        f32x4 kv = krow[idx];
        float m0 = mv.x + EPS_, m1 = mv.y + EPS_, m2 = mv.z + EPS_, m3 = mv.w + EPS_;
        float c0 = kv.x + EPS_, c1 = kv.y + EPS_, c2 = kv.z + EPS_, c3 = kv.w + EPS_;
        dacc += m0 * c0 + m1 * c1 + m2 * c2 + m3 * c3;
        nacc += m0 * m0 + m1 * m1 + m2 * m2 + m3 * m3;
    }
    dacc = wave_reduce_sum(dacc);
    nacc = wave_reduce_sum(nacc);
    if (lane == 0) {
        dot_out[row]    = dacc;
        mnorm2_out[row] = nacc;
    }
}

// ---------------- Pass 2: weight pipeline (recomputed per block) + write + read ----------------
// grid: B*SPLIT_ = 1024 blocks, 256 threads. Each block: full per-b weight
// pipeline (cheap, redundant x8), then erase/add + read partials on its 32 rows.
__global__ void fused_weight_write_kernel(const float* __restrict__ memory,
                                          const float* __restrict__ k,
                                          const float* __restrict__ beta,
                                          const float* __restrict__ g,
                                          const float* __restrict__ s,
                                          const float* __restrict__ gamma,
                                          const float* __restrict__ w_prev,
                                          const float* __restrict__ e,
                                          const float* __restrict__ a,
                                          const float* __restrict__ dot_in,
                                          const float* __restrict__ mnorm2_in,
                                          float* __restrict__ w_out,
                                          float* __restrict__ newmem_out,
                                          float* __restrict__ read_out) {
    const int b    = blockIdx.x >> 3;              // / SPLIT_
    const int part = blockIdx.x & (SPLIT_ - 1);
    const int tid  = threadIdx.x;                  // 0..255
    const int lane = tid & 63;
    const int wave = tid >> 6;
    const int n    = tid;

    __shared__ float red[4];
    __shared__ float s_wg[N_];

    // ---- knorm = max(||k+eps||, 1e-8) ----
    f32x4 kv = ((const f32x4*)(k + (size_t)b * M_))[tid];
    float k0 = kv.x + EPS_, k1 = kv.y + EPS_, k2 = kv.z + EPS_, k3 = kv.w + EPS_;
    float kk = k0 * k0 + k1 * k1 + k2 * k2 + k3 * k3;
    kk = wave_reduce_sum(kk);
    if (lane == 0) red[wave] = kk;
    __syncthreads();
    const float knorm = fmaxf(sqrtf(red[0] + red[1] + red[2] + red[3]), NORM_EPS_);
    __syncthreads();

    // ---- cosine + beta ----
    const float mnorm = fmaxf(sqrtf(mnorm2_in[(size_t)b * N_ + n]), NORM_EPS_);
    const float cosv  = dot_in[(size_t)b * N_ + n] / (mnorm * knorm);
    const float x     = beta[b] * cosv;

    // ---- softmax over n ----
    float mx = wave_reduce_max(x);
    if (lane == 0) red[wave] = mx;
    __syncthreads();
    mx = fmaxf(fmaxf(red[0], red[1]), fmaxf(red[2], red[3]));
    __syncthreads();
    const float ex = __expf(x - mx);
    float es = wave_reduce_sum(ex);
    if (lane == 0) red[wave] = es;
    __syncthreads();
    es = red[0] + red[1] + red[2] + red[3];
    __syncthreads();
    const float w_c = ex / es;

    // ---- interpolate ----
    const float gb  = g[b];
    const float w_g = gb * w_c + (1.f - gb) * w_prev[(size_t)b * N_ + n];
    s_wg[n] = w_g;
    __syncthreads();

    // ---- circular 3-tap shift ----
    const float s0 = s[b * 3 + 0], s1 = s[b * 3 + 1], s2 = s[b * 3 + 2];
    const float w_t = s0 * s_wg[(n + N_ - 1) & (N_ - 1)]
                    + s1 * s_wg[n]
                    + s2 * s_wg[(n + 1) & (N_ - 1)];
    __syncthreads();   // all shift reads done before s_wg is overwritten

    // ---- sharpen ----
    const float w_pow = powf(w_t, gamma[b]);
    float ps = wave_reduce_sum(w_pow);
    if (lane == 0) red[wave] = ps;
    __syncthreads();
    ps = red[0] + red[1] + red[2] + red[3];
    const float w_final = w_pow / (ps + EPS_);

    s_wg[n] = w_final;                  // reuse s_wg to hold final w
    if (part == 0) w_out[(size_t)b * N_ + n] = w_final;
    __syncthreads();

    // ---- write (erase/add) + fused read partials over this block's 32 rows ----
    const f32x4 ev = ((const f32x4*)(e + (size_t)b * M_))[tid];
    const f32x4 av = ((const f32x4*)(a + (size_t)b * M_))[tid];

    const size_t base = (size_t)b * N_ * M_;
    f32x4 racc = {0.f, 0.f, 0.f, 0.f};

#pragma unroll 4
    for (int j = 0; j < NSUB_; ++j) {
        const int nn = part * NSUB_ + j;
        const f32x4 mv = ((const f32x4*)(memory + base + (size_t)nn * M_))[tid];
        const float wn = s_wg[part * NSUB_ + j];
        f32x4 nv;
        nv.x = mv.x * (1.f - wn * ev.x) + wn * av.x;
        nv.y = mv.y * (1.f - wn * ev.y) + wn * av.y;
        nv.z = mv.z * (1.f - wn * ev.z) + wn * av.z;
        nv.w = mv.w * (1.f - wn * ev.w) + wn * av.w;
        ((f32x4*)(newmem_out + base + (size_t)nn * M_))[tid] = nv;
        racc.x += wn * nv.x;
        racc.y += wn * nv.y;
        racc.z += wn * nv.z;
        racc.w += wn * nv.w;
    }

    float* rrow = read_out + (size_t)b * M_ + tid * 4;
    atomicAdd(rrow + 0, racc.x);
    atomicAdd(rrow + 1, racc.y);
    atomicAdd(rrow + 2, racc.z);
    atomicAdd(rrow + 3, racc.w);
}

extern "C" void kernel_launch(void* const* d_in, const int* in_sizes, int n_in,
                              void* d_out, int out_size, void* d_ws, size_t ws_size,
                              hipStream_t stream) {
    (void)in_sizes; (void)n_in; (void)out_size; (void)ws_size;

    const float* memory = (const float*)d_in[0];
    const float* k      = (const float*)d_in[1];
    const float* beta   = (const float*)d_in[2];
    const float* g      = (const float*)d_in[3];
    const float* s      = (const float*)d_in[4];
    const float* gamma  = (const float*)d_in[5];
    const float* w_prev = (const float*)d_in[6];
    const float* e      = (const float*)d_in[7];
    const float* a      = (const float*)d_in[8];

    float* out        = (float*)d_out;
    float* read_out   = out;                                 // B*M
    float* newmem_out = out + (size_t)B_ * M_;               // B*N*M
    float* w_out      = newmem_out + (size_t)B_ * N_ * M_;   // B*N

    float* ws        = (float*)d_ws;
    float* dot_ws    = ws;                                   // B*N
    float* mnorm2_ws = ws + (size_t)B_ * N_;                 // B*N

    sim_kernel<<<(B_ * N_) / 4, 256, 0, stream>>>(memory, k, dot_ws, mnorm2_ws,
                                                  read_out);
    fused_weight_write_kernel<<<B_ * SPLIT_, 256, 0, stream>>>(
        memory, k, beta, g, s, gamma, w_prev, e, a,
        dot_ws, mnorm2_ws, w_out, newmem_out, read_out);
}